// Round 6
// baseline (2843.912 us; speedup 1.0000x reference)
//
#include <hip/hip_runtime.h>

typedef _Float16 f16;
typedef f16 f16x2 __attribute__((ext_vector_type(2)));
typedef f16 f16x8 __attribute__((ext_vector_type(8)));
typedef float f32x4 __attribute__((ext_vector_type(4)));
typedef float f32x16 __attribute__((ext_vector_type(16)));
typedef unsigned int uint;

#define NCH 16
#define NB 32
#define NH 256
#define NW 256
#define HW 65536
#define CHW 1048576

// ws/LDS weight image (f16 A-fragments + f32 bias fragments)
#define WF1 0            // f16 idx: [kt4][mt4][lane64][j8]
#define WF2 8192
#define WF3 24576
#define WF4 40960
#define BIAS_BYTE 90112  // 384 f32 bias frags
#define WS_BYTES 91648
// x tile: f16 [rr 18][cc 66][16 ch perm], stride 48B (16ch*2B + 16B pad)
#define LDS_XT_OFF 91648
#define XT_STRIDE 48
#define XT_BYTES (18*66*48)          // 57024
#define LDS_TOTAL (WS_BYTES + XT_BYTES)  // 148672

__global__ void prep_k(const float* __restrict__ w1, const float* __restrict__ w2,
                       const float* __restrict__ w3, const float* __restrict__ w4,
                       const float* __restrict__ b1, const float* __restrict__ b2,
                       const float* __restrict__ b3, float* __restrict__ wsf) {
  f16* wf = (f16*)wsf;
  int id = blockIdx.x * 256 + threadIdx.x;
  if (id < 8192) {
    int j = id & 7, l = (id >> 3) & 63, mt = (id >> 9) & 3, kt = id >> 11;
    int o = mt * 32 + (l & 31), c = kt * 16 + (l >> 5) * 8 + j;
    wf[WF1 + id] = (f16)w1[o * 64 + c];
  } else if (id < 24576) {
    int t = id - 8192;
    int j = t & 7, l = (t >> 3) & 63, mt = (t >> 9) & 3, kt = t >> 11;
    int o = mt * 32 + (l & 31), c = kt * 16 + (l >> 5) * 8 + j;
    wf[WF2 + t] = (f16)w2[o * 128 + c];
  } else if (id < 40960) {
    int t = id - 24576;
    int j = t & 7, l = (t >> 3) & 63, mt = (t >> 9) & 3, kt = t >> 11;
    int o = mt * 32 + (l & 31), c = kt * 16 + (l >> 5) * 8 + j;
    wf[WF3 + t] = (f16)w3[o * 128 + c];
  } else if (id < 45056) {
    int t = id - 40960;
    int j = t & 7, l = (t >> 3) & 63, kt = t >> 9;
    int m = l & 31, hh = l >> 5;
    int c = kt * 16 + hh * 8 + j;
    wf[WF4 + t] = (m < 16) ? (f16)w4[m * 128 + c] : (f16)0.f;
  } else if (id < 45440) {
    int t = id - 45056;
    int r = t & 15, hh = (t >> 4) & 1, mt = (t >> 5) & 3, ly = t >> 7;
    const float* bb = (ly == 0) ? b1 : (ly == 1) ? b2 : b3;
    ((float*)(wf + 45056))[t] = bb[mt * 32 + (r & 3) + 8 * (r >> 2) + 4 * hh];
  }
}

__device__ __forceinline__ void pl32swap(uint& a, uint& b) {
  asm volatile("v_permlane32_swap_b32 %0, %1" : "+v"(a), "+v"(b));
}

__device__ __forceinline__ f16x8 mk8(uint a, uint b, uint c, uint d) {
  union { uint u[4]; f16x8 v; } z;
  z.u[0] = a; z.u[1] = b; z.u[2] = c; z.u[3] = d;
  return z.v;
}

// One layer for BOTH 32-px halves; each A-fragment ds_read feeds 2 MFMAs.
template <int NKT>
__device__ __forceinline__ void gemm2(const unsigned char* __restrict__ smem,
                                      int wfByte, int biasFloatOff, int lane, int hi,
                                      const f16x8* __restrict__ BL,
                                      const f16x8* __restrict__ BH,
                                      f32x16 accL[4], f32x16 accH[4]) {
  const float* bf = (const float*)(smem + BIAS_BYTE) + biasFloatOff;
#pragma unroll
  for (int mt = 0; mt < 4; ++mt) {
    const f32x4* bp = (const f32x4*)(bf + (mt * 2 + hi) * 16);
#pragma unroll
    for (int q = 0; q < 4; ++q) {
      f32x4 bv = bp[q];
#pragma unroll
      for (int e = 0; e < 4; ++e) { accL[mt][q * 4 + e] = bv[e]; accH[mt][q * 4 + e] = bv[e]; }
    }
  }
  const f16x8* A = (const f16x8*)(smem + wfByte) + lane;
#pragma unroll
  for (int kt = 0; kt < NKT; ++kt) {
#pragma unroll
    for (int mt = 0; mt < 4; ++mt) {
      f16x8 a = A[(kt * 4 + mt) * 64];
      accL[mt] = __builtin_amdgcn_mfma_f32_32x32x16_f16(a, BL[kt], accL[mt], 0, 0, 0);
      accH[mt] = __builtin_amdgcn_mfma_f32_32x32x16_f16(a, BH[kt], accH[mt], 0, 0, 0);
    }
  }
}

// lrelu -> f16 pack -> permlane redistribution into next layer's B-frags
__device__ __forceinline__ void epilogue_swap(const f32x16 acc[4], f16x8 Bn[8]) {
  uint w[32];
#pragma unroll
  for (int mt = 0; mt < 4; ++mt) {
#pragma unroll
    for (int i = 0; i < 8; ++i) {
      float v0 = acc[mt][2 * i], v1 = acc[mt][2 * i + 1];
      v0 = fmaxf(v0, 0.01f * v0);
      v1 = fmaxf(v1, 0.01f * v1);
      f16x2 t; t[0] = (f16)v0; t[1] = (f16)v1;
      w[mt * 8 + i] = __builtin_bit_cast(uint, t);
    }
  }
#pragma unroll
  for (int kt = 0; kt < 8; ++kt) {
    int mt = kt >> 1, sub = kt & 1;
    int W = mt * 8 + sub * 4;
    uint a0 = w[W], a1 = w[W + 1], a2 = w[W + 2], a3 = w[W + 3];
    pl32swap(a0, a2);
    pl32swap(a1, a3);
    Bn[kt] = mk8(a0, a1, a2, a3);
  }
}

// perception for one 32-px half: one b128 per stencil position (8 channels)
__device__ __forceinline__ void perception(const unsigned char* __restrict__ xtb,
                                           int wv, int px, int hi, int h, f16x8 B1h[4]) {
  union U4 { uint4 u; f16 hh[8]; };
  const unsigned char* xp = xtb + (size_t)((wv * 66) + h * 32 + px) * XT_STRIDE + hi * 16;
  U4 q[9];
#pragma unroll
  for (int dr = 0; dr < 3; ++dr)
#pragma unroll
    for (int dc = 0; dc < 3; ++dc)
      q[dr * 3 + dc].u = *(const uint4*)(xp + (dr * 66 + dc) * XT_STRIDE);
  uint yw[16];
#pragma unroll
  for (int j = 0; j < 8; ++j) {
    float s0 = (float)q[0].hh[j], s1 = (float)q[1].hh[j], s2 = (float)q[2].hh[j];
    float s3 = (float)q[3].hh[j], s5 = (float)q[5].hh[j];
    float s6 = (float)q[6].hh[j], s7 = (float)q[7].hh[j], s8 = (float)q[8].hh[j];
    float c4 = (float)q[4].hh[j];
    float rs0 = s0 + s1 + s2, rs2 = s6 + s7 + s8;
    float fsx = (s2 - s0) + (s8 - s6) + 2.f * (s5 - s3);
    float fsy = (rs2 - rs0) + (s7 - s1);
    float flap = (rs0 + rs2 + s3 + s5) - 8.f * c4;
    f16x2 t0; t0[0] = q[4].hh[j]; t0[1] = (f16)fsx;
    f16x2 t1; t1[0] = (f16)fsy; t1[1] = (f16)flap;
    int kt = j >> 1, cp = j & 1;
    yw[kt * 4 + cp * 2 + 0] = __builtin_bit_cast(uint, t0);
    yw[kt * 4 + cp * 2 + 1] = __builtin_bit_cast(uint, t1);
  }
#pragma unroll
  for (int kt = 0; kt < 4; ++kt)
    B1h[kt] = mk8(yw[kt * 4], yw[kt * 4 + 1], yw[kt * 4 + 2], yw[kt * 4 + 3]);
}

__global__ __launch_bounds__(1024, 1)
void nca_mlp_k(const float* __restrict__ x, const float* __restrict__ wsf,
               const float* __restrict__ mask, float* __restrict__ xn) {
  extern __shared__ unsigned char smem[];
  const int tid = threadIdx.x;
  const int lane = tid & 63;
  const int wv = tid >> 6;      // 0..15 = tile row
  const int px = lane & 31;
  const int hi = lane >> 5;
  const int c0 = blockIdx.x * 64;
  const int r0 = blockIdx.y * 16;
  const int b = blockIdx.z;

  // ---- stage weights+bias into LDS ----
  {
    const uint4* src = (const uint4*)wsf;
    uint4* dst = (uint4*)smem;
#pragma unroll
    for (int i = 0; i < 6; ++i) {
      int idx = tid + i * 1024;
      if (idx < WS_BYTES / 16) dst[idx] = src[idx];
    }
  }
  // ---- stage x tile as f16, channel-permuted ----
  unsigned char* xtb = smem + LDS_XT_OFF;
  {
    const float* xb = x + (size_t)b * CHW;
    int ch = tid >> 6;
    int cc = (tid & 63) + 1;
    int sidx = ((ch >> 1) & 1) * 8 + (ch >> 2) * 2 + (ch & 1);
    int gc = c0 + (tid & 63);
#pragma unroll 1
    for (int rr = 0; rr < 18; ++rr) {
      int gr = r0 - 1 + rr;
      float v = 0.f;
      if ((unsigned)gr < NH) v = xb[(ch << 16) + (gr << 8) + gc];
      *(f16*)(xtb + (rr * 66 + cc) * XT_STRIDE + sidx * 2) = (f16)v;
    }
    if (tid < 576) {
      int rr = tid >> 5;
      int ch2 = (tid >> 1) & 15;
      int side = tid & 1;
      int cc2 = side * 65;
      int gr = r0 - 1 + rr, gc2 = c0 - 1 + cc2;
      float v = 0.f;
      if ((unsigned)gr < NH && (unsigned)gc2 < NW) v = xb[(ch2 << 16) + (gr << 8) + gc2];
      int s2 = ((ch2 >> 1) & 1) * 8 + (ch2 >> 2) * 2 + (ch2 & 1);
      *(f16*)(xtb + (rr * 66 + cc2) * XT_STRIDE + s2 * 2) = (f16)v;
    }
  }
  __syncthreads();

  // ---- perception: both halves ----
  f16x8 B1L[4], B1H[4];
  perception(xtb, wv, px, hi, 0, B1L);
  perception(xtb, wv, px, hi, 1, B1H);

  f32x16 accL[4], accH[4];
  f16x8 B2L[8], B2H[8], B3L[8], B3H[8], B4L[8], B4H[8];

  gemm2<4>(smem, WF1 * 2, 0, lane, hi, B1L, B1H, accL, accH);
  epilogue_swap(accL, B2L);
  epilogue_swap(accH, B2H);
  gemm2<8>(smem, WF2 * 2, 128, lane, hi, B2L, B2H, accL, accH);
  epilogue_swap(accL, B3L);
  epilogue_swap(accH, B3H);
  gemm2<8>(smem, WF3 * 2, 256, lane, hi, B3L, B3H, accL, accH);
  epilogue_swap(accL, B4L);
  epilogue_swap(accH, B4H);

  // ---- layer 4 (M padded to 32), shared A-frags across halves ----
  f32x16 a4L, a4H;
#pragma unroll
  for (int r = 0; r < 16; ++r) { a4L[r] = 0.f; a4H[r] = 0.f; }
  {
    const f16x8* A4 = (const f16x8*)(smem + WF4 * 2) + lane;
#pragma unroll
    for (int kt = 0; kt < 8; ++kt) {
      f16x8 a = A4[kt * 64];
      a4L = __builtin_amdgcn_mfma_f32_32x32x16_f16(a, B4L[kt], a4L, 0, 0, 0);
      a4H = __builtin_amdgcn_mfma_f32_32x32x16_f16(a, B4H[kt], a4H, 0, 0, 0);
    }
  }

  // ---- update: x_new = x + dy * mask (exact f32 x re-read, L2-hot) ----
  {
    const int row = r0 + wv;
    const float* xrb = x + (size_t)b * CHW + (row << 8);
    float* xob = xn + (size_t)b * CHW + (row << 8);
    const float* mrow = mask + (size_t)b * HW + (row << 8);
#pragma unroll
    for (int h = 0; h < 2; ++h) {
      int col = c0 + h * 32 + px;
      float mv = mrow[col];
#pragma unroll
      for (int r = 0; r < 8; ++r) {
        int m = (r & 3) + 8 * (r >> 2) + 4 * hi;
        float dy = h ? a4H[r] : a4L[r];
        xob[((size_t)m << 16) + col] = xrb[((size_t)m << 16) + col] + dy * mv;
      }
    }
  }
}

// alive factor: row-block with LDS horizontal-max sharing; zero dead pixels
__global__ void alive_scale_k(const float* __restrict__ x, float* __restrict__ xn) {
  __shared__ float pm[4][258];
  const int col = threadIdx.x;
  const int row = blockIdx.x;
  const int b = blockIdx.y;
  const float NEG = -3.0e38f;
  float v0 = NEG, v1 = NEG, v2 = NEG, v3 = NEG;
  const size_t base0 = (size_t)b * CHW + ((size_t)row << 8) + col;
#pragma unroll
  for (int dr = -1; dr <= 1; ++dr) {
    int rr = row + dr;
    if ((unsigned)rr < NH) {
      long o = (long)base0 + dr * NW;
      v0 = fmaxf(v0, x[o]);
      v1 = fmaxf(v1, x[o + HW]);
      v2 = fmaxf(v2, xn[o]);
      v3 = fmaxf(v3, xn[o + HW]);
    }
  }
  pm[0][col + 1] = v0;
  pm[1][col + 1] = v1;
  pm[2][col + 1] = v2;
  pm[3][col + 1] = v3;
  if (col == 0) {
#pragma unroll
    for (int f = 0; f < 4; ++f) { pm[f][0] = NEG; pm[f][257] = NEG; }
  }
  __syncthreads();
  float p0 = fmaxf(fmaxf(pm[0][col], pm[0][col + 1]), pm[0][col + 2]);
  float p1 = fmaxf(fmaxf(pm[1][col], pm[1][col + 1]), pm[1][col + 2]);
  float p2 = fmaxf(fmaxf(pm[2][col], pm[2][col + 1]), pm[2][col + 2]);
  float p3 = fmaxf(fmaxf(pm[3][col], pm[3][col + 1]), pm[3][col + 2]);
  bool alive = ((fabsf(p0) + fabsf(p1)) > 0.01f) && ((fabsf(p2) + fabsf(p3)) > 0.01f);
  if (!alive) {
#pragma unroll
    for (int ch = 0; ch < NCH; ++ch) xn[base0 + ((size_t)ch << 16)] = 0.f;
  }
}

extern "C" void kernel_launch(void* const* d_in, const int* in_sizes, int n_in,
                              void* d_out, int out_size, void* d_ws, size_t ws_size,
                              hipStream_t stream) {
  const float* x    = (const float*)d_in[0];
  const float* w1   = (const float*)d_in[1];
  const float* b1   = (const float*)d_in[2];
  const float* w2   = (const float*)d_in[3];
  const float* b2   = (const float*)d_in[4];
  const float* w3   = (const float*)d_in[5];
  const float* b3   = (const float*)d_in[6];
  const float* w4   = (const float*)d_in[7];
  const float* mask = (const float*)d_in[8];

  float* wsf = (float*)d_ws;
  float* xn = (float*)d_out;

  hipFuncSetAttribute(reinterpret_cast<const void*>(nca_mlp_k),
                      hipFuncAttributeMaxDynamicSharedMemorySize, LDS_TOTAL);

  prep_k<<<178, 256, 0, stream>>>(w1, w2, w3, w4, b1, b2, b3, wsf);
  nca_mlp_k<<<dim3(NW / 64, NH / 16, NB), 1024, LDS_TOTAL, stream>>>(x, wsf, mask, xn);
  alive_scale_k<<<dim3(NH, NB), 256, 0, stream>>>(x, xn);
}

// Round 7
// 783.717 us; speedup vs baseline: 3.6287x; 3.6287x over previous
//
#include <hip/hip_runtime.h>

typedef _Float16 f16;
typedef f16 f16x2 __attribute__((ext_vector_type(2)));
typedef f16 f16x8 __attribute__((ext_vector_type(8)));
typedef float f32x4 __attribute__((ext_vector_type(4)));
typedef float f32x16 __attribute__((ext_vector_type(16)));
typedef unsigned int uint;

#define NCH 16
#define NB 32
#define NH 256
#define NW 256
#define HW 65536
#define CHW 1048576

// ws weight image (f16 A-fragments + f32 bias fragments), produced by prep_k
// f16 idx: WF1 [kt4][mt4][lane64][j8]=8192, WF2=+16384, WF3=+16384, WF4 [kt8][lane][j8]=4096
// float idx 22528: bias frags [ly3][mt4][hi2][r16]
#define BIAS_F32 22528

// LDS partitions (dynamic)
#define XT_OFF 0                  // f32 [ch16][rr6][cc34] = 13056 B
#define ACT1_OFF 13056            // f16 [p128][row 128B] swizzled = 16384
#define ACTA_OFF 29440            // f16 [p128][row 256B] swizzled = 32768
#define ACTB_OFF 62208            // 32768
#define DY_OFF 94976              // f32 [o16][p128] = 8192
#define LDS_TOTAL 103168

#define ABYTE1(p, c) ((p) * 128 + (((c) * 2) ^ (((p) & 7) << 4)))
#define ABYTE2(p, c) ((p) * 256 + (((c) * 2) ^ (((p) & 15) << 4)))

__global__ void prep_k(const float* __restrict__ w1, const float* __restrict__ w2,
                       const float* __restrict__ w3, const float* __restrict__ w4,
                       const float* __restrict__ b1, const float* __restrict__ b2,
                       const float* __restrict__ b3, float* __restrict__ wsf) {
  f16* wf = (f16*)wsf;
  int id = blockIdx.x * 256 + threadIdx.x;
  if (id < 8192) {
    int j = id & 7, l = (id >> 3) & 63, mt = (id >> 9) & 3, kt = id >> 11;
    int o = mt * 32 + (l & 31), c = kt * 16 + (l >> 5) * 8 + j;
    wf[id] = (f16)w1[o * 64 + c];
  } else if (id < 24576) {
    int t = id - 8192;
    int j = t & 7, l = (t >> 3) & 63, mt = (t >> 9) & 3, kt = t >> 11;
    int o = mt * 32 + (l & 31), c = kt * 16 + (l >> 5) * 8 + j;
    wf[8192 + t] = (f16)w2[o * 128 + c];
  } else if (id < 40960) {
    int t = id - 24576;
    int j = t & 7, l = (t >> 3) & 63, mt = (t >> 9) & 3, kt = t >> 11;
    int o = mt * 32 + (l & 31), c = kt * 16 + (l >> 5) * 8 + j;
    wf[24576 + t] = (f16)w3[o * 128 + c];
  } else if (id < 45056) {
    int t = id - 40960;
    int j = t & 7, l = (t >> 3) & 63, kt = t >> 9;
    int m = l & 31, hh = l >> 5;
    int c = kt * 16 + hh * 8 + j;
    wf[40960 + t] = (m < 16) ? (f16)w4[m * 128 + c] : (f16)0.f;
  } else if (id < 45440) {
    int t = id - 45056;
    int r = t & 15, hh = (t >> 4) & 1, mt = (t >> 5) & 3, ly = t >> 7;
    const float* bb = (ly == 0) ? b1 : (ly == 1) ? b2 : b3;
    wsf[BIAS_F32 + t] = bb[mt * 32 + (r & 3) + 8 * (r >> 2) + 4 * hh];
  }
}

__global__ __launch_bounds__(256, 1)
void nca_mlp_k(const float* __restrict__ x, const float* __restrict__ wsf,
               const float* __restrict__ mask, float* __restrict__ xn) {
  extern __shared__ unsigned char smem[];
  float* xt = (float*)smem;                       // [ch][rr6][cc34]
  unsigned char* act1 = smem + ACT1_OFF;
  unsigned char* actA = smem + ACTA_OFF;
  unsigned char* actB = smem + ACTB_OFF;
  float* dy = (float*)(smem + DY_OFF);

  const int tid = threadIdx.x;
  const int lane = tid & 63;
  const int wv = tid >> 6;       // wave = mt slice (and pxtile for L4/perception)
  const int pc = lane & 31;
  const int hi = lane >> 5;
  const int c0 = blockIdx.x * 32;
  const int r0 = blockIdx.y * 4;
  const int b = blockIdx.z;

  // ---- weights into registers (per-wave mt slice; A4 replicated) ----
  const f16x8* wp = (const f16x8*)wsf;
  f16x8 A1[4], A2[8], A3[8], A4[8];
#pragma unroll
  for (int kt = 0; kt < 4; ++kt) A1[kt] = wp[(kt * 4 + wv) * 64 + lane];
#pragma unroll
  for (int kt = 0; kt < 8; ++kt) A2[kt] = wp[1024 + (kt * 4 + wv) * 64 + lane];
#pragma unroll
  for (int kt = 0; kt < 8; ++kt) A3[kt] = wp[3072 + (kt * 4 + wv) * 64 + lane];
#pragma unroll
  for (int kt = 0; kt < 8; ++kt) A4[kt] = wp[5120 + kt * 64 + lane];

  // ---- stage x tile f32 (zero-padded halo) ----
  {
    const float* xb = x + (size_t)b * CHW;
    for (int i = tid; i < 16 * 6 * 34; i += 256) {
      int cc = i % 34;
      int seg = i / 34;
      int rr = seg % 6;
      int ch = seg / 6;
      int gr = r0 - 1 + rr, gc = c0 - 1 + cc;
      float v = 0.f;
      if ((unsigned)gr < NH && (unsigned)gc < NW) v = xb[(ch << 16) + (gr << 8) + gc];
      xt[(ch * 6 + rr) * 34 + cc] = v;
    }
  }
  __syncthreads();

  // ---- perception: wave wv computes pxtile wv (row wv of tile), 8 ch per lane ----
  {
    const int p = wv * 32 + pc;
#pragma unroll
    for (int j = 0; j < 8; ++j) {
      int ch = hi * 8 + j;
      const float* xr = &xt[(ch * 6 + wv) * 34 + pc];
      float v00 = xr[0],      v01 = xr[1],      v02 = xr[2];
      float v10 = xr[34],     v11 = xr[35],     v12 = xr[36];
      float v20 = xr[68],     v21 = xr[69],     v22 = xr[70];
      float rs0 = v00 + v01 + v02, rs2 = v20 + v21 + v22;
      float fsx = (v02 - v00) + (v22 - v20) + 2.f * (v12 - v10);
      float fsy = (rs2 - rs0) + (v21 - v01);
      float flap = (rs0 + rs2 + v10 + v12) - 8.f * v11;
      int c = 32 * hi + 4 * j;
      f16x2 t0; t0[0] = (f16)v11; t0[1] = (f16)fsx;
      f16x2 t1; t1[0] = (f16)fsy; t1[1] = (f16)flap;
      *(f16x2*)(act1 + ABYTE1(p, c)) = t0;
      *(f16x2*)(act1 + ABYTE1(p, c + 2)) = t1;
    }
  }
  __syncthreads();

  f32x16 acc[4];

  // ---- L1: act1 (K=64) -> actA ----
  {
#pragma unroll
    for (int q = 0; q < 4; ++q) {
      f32x4 bv = *(const f32x4*)(wsf + BIAS_F32 + wv * 32 + hi * 16 + q * 4);
#pragma unroll
      for (int t = 0; t < 4; ++t)
#pragma unroll
        for (int e = 0; e < 4; ++e) acc[t][q * 4 + e] = bv[e];
    }
#pragma unroll
    for (int kt = 0; kt < 4; ++kt)
#pragma unroll
      for (int t = 0; t < 4; ++t) {
        f16x8 bf = *(const f16x8*)(act1 + ABYTE1(t * 32 + pc, kt * 16 + hi * 8));
        acc[t] = __builtin_amdgcn_mfma_f32_32x32x16_f16(A1[kt], bf, acc[t], 0, 0, 0);
      }
#pragma unroll
    for (int t = 0; t < 4; ++t) {
      int p = t * 32 + pc;
#pragma unroll
      for (int r = 0; r < 16; r += 2) {
        float v0 = acc[t][r], v1 = acc[t][r + 1];
        v0 = fmaxf(v0, 0.01f * v0);
        v1 = fmaxf(v1, 0.01f * v1);
        int o = wv * 32 + (r & 3) + 8 * (r >> 2) + 4 * hi;
        f16x2 pr; pr[0] = (f16)v0; pr[1] = (f16)v1;
        *(f16x2*)(actA + ABYTE2(p, o)) = pr;
      }
    }
  }
  __syncthreads();

  // ---- L2: actA (K=128) -> actB ----
  {
#pragma unroll
    for (int q = 0; q < 4; ++q) {
      f32x4 bv = *(const f32x4*)(wsf + BIAS_F32 + 128 + wv * 32 + hi * 16 + q * 4);
#pragma unroll
      for (int t = 0; t < 4; ++t)
#pragma unroll
        for (int e = 0; e < 4; ++e) acc[t][q * 4 + e] = bv[e];
    }
#pragma unroll
    for (int kt = 0; kt < 8; ++kt)
#pragma unroll
      for (int t = 0; t < 4; ++t) {
        f16x8 bf = *(const f16x8*)(actA + ABYTE2(t * 32 + pc, kt * 16 + hi * 8));
        acc[t] = __builtin_amdgcn_mfma_f32_32x32x16_f16(A2[kt], bf, acc[t], 0, 0, 0);
      }
#pragma unroll
    for (int t = 0; t < 4; ++t) {
      int p = t * 32 + pc;
#pragma unroll
      for (int r = 0; r < 16; r += 2) {
        float v0 = acc[t][r], v1 = acc[t][r + 1];
        v0 = fmaxf(v0, 0.01f * v0);
        v1 = fmaxf(v1, 0.01f * v1);
        int o = wv * 32 + (r & 3) + 8 * (r >> 2) + 4 * hi;
        f16x2 pr; pr[0] = (f16)v0; pr[1] = (f16)v1;
        *(f16x2*)(actB + ABYTE2(p, o)) = pr;
      }
    }
  }
  __syncthreads();

  // ---- L3: actB (K=128) -> actA ----
  {
#pragma unroll
    for (int q = 0; q < 4; ++q) {
      f32x4 bv = *(const f32x4*)(wsf + BIAS_F32 + 256 + wv * 32 + hi * 16 + q * 4);
#pragma unroll
      for (int t = 0; t < 4; ++t)
#pragma unroll
        for (int e = 0; e < 4; ++e) acc[t][q * 4 + e] = bv[e];
    }
#pragma unroll
    for (int kt = 0; kt < 8; ++kt)
#pragma unroll
      for (int t = 0; t < 4; ++t) {
        f16x8 bf = *(const f16x8*)(actB + ABYTE2(t * 32 + pc, kt * 16 + hi * 8));
        acc[t] = __builtin_amdgcn_mfma_f32_32x32x16_f16(A3[kt], bf, acc[t], 0, 0, 0);
      }
#pragma unroll
    for (int t = 0; t < 4; ++t) {
      int p = t * 32 + pc;
#pragma unroll
      for (int r = 0; r < 16; r += 2) {
        float v0 = acc[t][r], v1 = acc[t][r + 1];
        v0 = fmaxf(v0, 0.01f * v0);
        v1 = fmaxf(v1, 0.01f * v1);
        int o = wv * 32 + (r & 3) + 8 * (r >> 2) + 4 * hi;
        f16x2 pr; pr[0] = (f16)v0; pr[1] = (f16)v1;
        *(f16x2*)(actA + ABYTE2(p, o)) = pr;
      }
    }
  }
  __syncthreads();

  // ---- L4: wave wv computes dy for pxtile wv (M padded to 32) ----
  {
    f32x16 a4;
#pragma unroll
    for (int r = 0; r < 16; ++r) a4[r] = 0.f;
    const int p = wv * 32 + pc;
#pragma unroll
    for (int kt = 0; kt < 8; ++kt) {
      f16x8 bf = *(const f16x8*)(actA + ABYTE2(p, kt * 16 + hi * 8));
      a4 = __builtin_amdgcn_mfma_f32_32x32x16_f16(A4[kt], bf, a4, 0, 0, 0);
    }
#pragma unroll
    for (int r = 0; r < 8; ++r) {
      int o = (r & 3) + 8 * (r >> 2) + 4 * hi;
      dy[o * 128 + p] = a4[r];
    }
  }
  __syncthreads();

  // ---- update: x_new = x + dy * mask (exact f32 from xt) ----
  {
    const int p = tid & 127;
    const int g = tid >> 7;
    const int pr = p >> 5, pcc = p & 31;
    const int row = r0 + pr, col = c0 + pcc;
    const float mv = mask[(size_t)b * HW + (row << 8) + col];
    float* xo = xn + (size_t)b * CHW + (row << 8) + col;
#pragma unroll
    for (int i = 0; i < 8; ++i) {
      int ch = g * 8 + i;
      float xv = xt[(ch * 6 + pr + 1) * 34 + pcc + 1];
      xo[(size_t)ch << 16] = xv + dy[ch * 128 + p] * mv;
    }
  }
}

// alive factor: row-block with LDS horizontal-max sharing; zero dead pixels
__global__ void alive_scale_k(const float* __restrict__ x, float* __restrict__ xn) {
  __shared__ float pm[4][258];
  const int col = threadIdx.x;
  const int row = blockIdx.x;
  const int b = blockIdx.y;
  const float NEG = -3.0e38f;
  float v0 = NEG, v1 = NEG, v2 = NEG, v3 = NEG;
  const size_t base0 = (size_t)b * CHW + ((size_t)row << 8) + col;
#pragma unroll
  for (int dr = -1; dr <= 1; ++dr) {
    int rr = row + dr;
    if ((unsigned)rr < NH) {
      long o = (long)base0 + dr * NW;
      v0 = fmaxf(v0, x[o]);
      v1 = fmaxf(v1, x[o + HW]);
      v2 = fmaxf(v2, xn[o]);
      v3 = fmaxf(v3, xn[o + HW]);
    }
  }
  pm[0][col + 1] = v0;
  pm[1][col + 1] = v1;
  pm[2][col + 1] = v2;
  pm[3][col + 1] = v3;
  if (col == 0) {
#pragma unroll
    for (int f = 0; f < 4; ++f) { pm[f][0] = NEG; pm[f][257] = NEG; }
  }
  __syncthreads();
  float p0 = fmaxf(fmaxf(pm[0][col], pm[0][col + 1]), pm[0][col + 2]);
  float p1 = fmaxf(fmaxf(pm[1][col], pm[1][col + 1]), pm[1][col + 2]);
  float p2 = fmaxf(fmaxf(pm[2][col], pm[2][col + 1]), pm[2][col + 2]);
  float p3 = fmaxf(fmaxf(pm[3][col], pm[3][col + 1]), pm[3][col + 2]);
  bool alive = ((fabsf(p0) + fabsf(p1)) > 0.01f) && ((fabsf(p2) + fabsf(p3)) > 0.01f);
  if (!alive) {
#pragma unroll
    for (int ch = 0; ch < NCH; ++ch) xn[base0 + ((size_t)ch << 16)] = 0.f;
  }
}

extern "C" void kernel_launch(void* const* d_in, const int* in_sizes, int n_in,
                              void* d_out, int out_size, void* d_ws, size_t ws_size,
                              hipStream_t stream) {
  const float* x    = (const float*)d_in[0];
  const float* w1   = (const float*)d_in[1];
  const float* b1   = (const float*)d_in[2];
  const float* w2   = (const float*)d_in[3];
  const float* b2   = (const float*)d_in[4];
  const float* w3   = (const float*)d_in[5];
  const float* b3   = (const float*)d_in[6];
  const float* w4   = (const float*)d_in[7];
  const float* mask = (const float*)d_in[8];

  float* wsf = (float*)d_ws;
  float* xn = (float*)d_out;

  hipFuncSetAttribute(reinterpret_cast<const void*>(nca_mlp_k),
                      hipFuncAttributeMaxDynamicSharedMemorySize, LDS_TOTAL);

  prep_k<<<178, 256, 0, stream>>>(w1, w2, w3, w4, b1, b2, b3, wsf);
  nca_mlp_k<<<dim3(NW / 32, NH / 4, NB), 256, LDS_TOTAL, stream>>>(x, wsf, mask, xn);
  alive_scale_k<<<dim3(NH, NB), 256, 0, stream>>>(x, xn);
}

// Round 8
// 423.059 us; speedup vs baseline: 6.7223x; 1.8525x over previous
//
#include <hip/hip_runtime.h>

typedef _Float16 f16;
typedef f16 f16x2 __attribute__((ext_vector_type(2)));
typedef f16 f16x8 __attribute__((ext_vector_type(8)));
typedef float f32x4 __attribute__((ext_vector_type(4)));
typedef float f32x16 __attribute__((ext_vector_type(16)));
typedef unsigned int uint;

#define NCH 16
#define NB 32
#define NH 256
#define NW 256
#define HW 65536
#define CHW 1048576

// weight image (f16 A-frags + f32 bias frags): f16x8 idx WF1=0, WF2=1024, WF3=3072, WF4=5120
#define BIAS_BYTE 90112
#define WS_BYTES 91648
// x tile: f16 [rr10][cc66][ch16 perm] = 32B/px, conflict-free
#define XT_OFF 91648
#define XT_POS (10*66)
#define LDS_TOTAL (WS_BYTES + XT_POS*32)   // 112768

__global__ void prep_k(const float* __restrict__ w1, const float* __restrict__ w2,
                       const float* __restrict__ w3, const float* __restrict__ w4,
                       const float* __restrict__ b1, const float* __restrict__ b2,
                       const float* __restrict__ b3, float* __restrict__ wsf) {
  f16* wf = (f16*)wsf;
  int id = blockIdx.x * 256 + threadIdx.x;
  if (id < 8192) {
    int j = id & 7, l = (id >> 3) & 63, mt = (id >> 9) & 3, kt = id >> 11;
    int o = mt * 32 + (l & 31), c = kt * 16 + (l >> 5) * 8 + j;
    wf[id] = (f16)w1[o * 64 + c];
  } else if (id < 24576) {
    int t = id - 8192;
    int j = t & 7, l = (t >> 3) & 63, mt = (t >> 9) & 3, kt = t >> 11;
    int o = mt * 32 + (l & 31), c = kt * 16 + (l >> 5) * 8 + j;
    wf[8192 + t] = (f16)w2[o * 128 + c];
  } else if (id < 40960) {
    int t = id - 24576;
    int j = t & 7, l = (t >> 3) & 63, mt = (t >> 9) & 3, kt = t >> 11;
    int o = mt * 32 + (l & 31), c = kt * 16 + (l >> 5) * 8 + j;
    wf[24576 + t] = (f16)w3[o * 128 + c];
  } else if (id < 45056) {
    int t = id - 40960;
    int j = t & 7, l = (t >> 3) & 63, kt = t >> 9;
    int m = l & 31, hh = l >> 5;
    int c = kt * 16 + hh * 8 + j;
    wf[40960 + t] = (m < 16) ? (f16)w4[m * 128 + c] : (f16)0.f;
  } else if (id < 45440) {
    int t = id - 45056;
    int r = t & 15, hh = (t >> 4) & 1, mt = (t >> 5) & 3, ly = t >> 7;
    const float* bb = (ly == 0) ? b1 : (ly == 1) ? b2 : b3;
    ((float*)((unsigned char*)wsf + BIAS_BYTE))[t] =
        bb[mt * 32 + (r & 3) + 8 * (r >> 2) + 4 * hh];
  }
}

__device__ __forceinline__ void pl32swap(uint& a, uint& b) {
  asm volatile("v_permlane32_swap_b32 %0, %1" : "+v"(a), "+v"(b));
}

__device__ __forceinline__ f16x8 mk8(uint a, uint b, uint c, uint d) {
  union { uint u[4]; f16x8 v; } z;
  z.u[0] = a; z.u[1] = b; z.u[2] = c; z.u[3] = d;
  return z.v;
}

// Dual-half layer: each A-frag ds_read feeds 2 MFMAs (halves L and H)
template <int NKT>
__device__ __forceinline__ void gemm2(const unsigned char* __restrict__ smem,
                                      int wfFragBase, int biasFloatOff, int lane, int hi,
                                      const f16x8* __restrict__ BL,
                                      const f16x8* __restrict__ BH,
                                      f32x16 accL[4], f32x16 accH[4]) {
  const float* bf = (const float*)(smem + BIAS_BYTE) + biasFloatOff;
#pragma unroll
  for (int mt = 0; mt < 4; ++mt) {
#pragma unroll
    for (int q = 0; q < 4; ++q) {
      f32x4 bv = *(const f32x4*)(bf + (mt * 2 + hi) * 16 + q * 4);
#pragma unroll
      for (int e = 0; e < 4; ++e) { accL[mt][q * 4 + e] = bv[e]; accH[mt][q * 4 + e] = bv[e]; }
    }
  }
  const f16x8* A = (const f16x8*)smem + wfFragBase + lane;
#pragma unroll
  for (int kt = 0; kt < NKT; ++kt) {
#pragma unroll
    for (int mt = 0; mt < 4; ++mt) {
      f16x8 a = A[(kt * 4 + mt) * 64];
      accL[mt] = __builtin_amdgcn_mfma_f32_32x32x16_f16(a, BL[kt], accL[mt], 0, 0, 0);
      accH[mt] = __builtin_amdgcn_mfma_f32_32x32x16_f16(a, BH[kt], accH[mt], 0, 0, 0);
    }
  }
}

__device__ __forceinline__ void epilogue_swap(const f32x16 acc[4], f16x8 Bn[8]) {
  uint w[32];
#pragma unroll
  for (int mt = 0; mt < 4; ++mt) {
#pragma unroll
    for (int i = 0; i < 8; ++i) {
      float v0 = acc[mt][2 * i], v1 = acc[mt][2 * i + 1];
      v0 = fmaxf(v0, 0.01f * v0);
      v1 = fmaxf(v1, 0.01f * v1);
      f16x2 t; t[0] = (f16)v0; t[1] = (f16)v1;
      w[mt * 8 + i] = __builtin_bit_cast(uint, t);
    }
  }
#pragma unroll
  for (int kt = 0; kt < 8; ++kt) {
    int mt = kt >> 1, sub = kt & 1;
    int W = mt * 8 + sub * 4;
    uint a0 = w[W], a1 = w[W + 1], a2 = w[W + 2], a3 = w[W + 3];
    pl32swap(a0, a2);
    pl32swap(a1, a3);
    Bn[kt] = mk8(a0, a1, a2, a3);
  }
}

// perception for one 32-px half: 9 b128 reads (8 permuted channels each)
__device__ __forceinline__ void perception(const unsigned char* __restrict__ xtb,
                                           int wv, int pc, int hi, int h, f16x8 B1h[4]) {
  union U4 { uint4 u; f16 hh[8]; };
  const unsigned char* xp = xtb + (size_t)(wv * 66 + h * 32 + pc) * 32 + hi * 16;
  U4 q[9];
#pragma unroll
  for (int dr = 0; dr < 3; ++dr)
#pragma unroll
    for (int dc = 0; dc < 3; ++dc)
      q[dr * 3 + dc].u = *(const uint4*)(xp + (dr * 66 + dc) * 32);
  uint yw[16];
#pragma unroll
  for (int j = 0; j < 8; ++j) {
    float s0 = (float)q[0].hh[j], s1 = (float)q[1].hh[j], s2 = (float)q[2].hh[j];
    float s3 = (float)q[3].hh[j], s5 = (float)q[5].hh[j];
    float s6 = (float)q[6].hh[j], s7 = (float)q[7].hh[j], s8 = (float)q[8].hh[j];
    float c4 = (float)q[4].hh[j];
    float rs0 = s0 + s1 + s2, rs2 = s6 + s7 + s8;
    float fsx = (s2 - s0) + (s8 - s6) + 2.f * (s5 - s3);
    float fsy = (rs2 - rs0) + (s7 - s1);
    float flap = (rs0 + rs2 + s3 + s5) - 8.f * c4;
    f16x2 t0; t0[0] = q[4].hh[j]; t0[1] = (f16)fsx;
    f16x2 t1; t1[0] = (f16)fsy; t1[1] = (f16)flap;
    int kt = j >> 1, cp = j & 1;
    yw[kt * 4 + cp * 2 + 0] = __builtin_bit_cast(uint, t0);
    yw[kt * 4 + cp * 2 + 1] = __builtin_bit_cast(uint, t1);
  }
#pragma unroll
  for (int kt = 0; kt < 4; ++kt)
    B1h[kt] = mk8(yw[kt * 4], yw[kt * 4 + 1], yw[kt * 4 + 2], yw[kt * 4 + 3]);
}

__global__ __launch_bounds__(512, 2)
void nca_mlp_k(const float* __restrict__ x, const float* __restrict__ wsf,
               const float* __restrict__ mask, float* __restrict__ xn) {
  extern __shared__ unsigned char smem[];
  unsigned char* xtb = smem + XT_OFF;
  const int tid = threadIdx.x;
  const int lane = tid & 63;
  const int wv = tid >> 6;     // 0..7 = tile row
  const int pc = lane & 31;
  const int hi = lane >> 5;
  const int c0 = blockIdx.x * 64;
  const int r0 = blockIdx.y * 8;
  const int b = blockIdx.z;

  // ---- stage weights+bias (linear b128 copy) ----
  {
    const uint4* src = (const uint4*)wsf;
    uint4* dst = (uint4*)smem;
    for (int i = tid; i < WS_BYTES / 16; i += 512) dst[i] = src[i];
  }
  // ---- stage x tile: f16, channel-permuted [rr][cc][16] ----
  {
    const float* xb = x + (size_t)b * CHW;
    for (int i = tid; i < XT_POS; i += 512) {
      int rr = i / 66, cc = i - rr * 66;
      int gr = r0 - 1 + rr, gc = c0 - 1 + cc;
      bool ok = ((unsigned)gr < NH) && ((unsigned)gc < NW);
      union { f16 h[16]; uint4 u4[2]; } z;
#pragma unroll
      for (int ch = 0; ch < 16; ++ch) {
        float v = ok ? xb[(ch << 16) + (gr << 8) + gc] : 0.f;
        int s = ((ch >> 1) & 1) * 8 + (ch >> 2) * 2 + (ch & 1);
        z.h[s] = (f16)v;
      }
      uint4* dp = (uint4*)(xtb + i * 32);
      dp[0] = z.u4[0];
      dp[1] = z.u4[1];
    }
  }
  __syncthreads();

  // ---- perception both halves ----
  f16x8 B1L[4], B1H[4];
  perception(xtb, wv, pc, hi, 0, B1L);
  perception(xtb, wv, pc, hi, 1, B1H);

  f32x16 accL[4], accH[4];
  f16x8 B2L[8], B2H[8], B3L[8], B3H[8], B4L[8], B4H[8];

  gemm2<4>(smem, 0, 0, lane, hi, B1L, B1H, accL, accH);
  epilogue_swap(accL, B2L);
  epilogue_swap(accH, B2H);
  gemm2<8>(smem, 1024, 128, lane, hi, B2L, B2H, accL, accH);
  epilogue_swap(accL, B3L);
  epilogue_swap(accH, B3H);
  gemm2<8>(smem, 3072, 256, lane, hi, B3L, B3H, accL, accH);
  epilogue_swap(accL, B4L);
  epilogue_swap(accH, B4H);

  // ---- layer 4 (M padded to 32), A-frags shared across halves ----
  f32x16 a4L, a4H;
#pragma unroll
  for (int r = 0; r < 16; ++r) { a4L[r] = 0.f; a4H[r] = 0.f; }
  {
    const f16x8* A4 = (const f16x8*)smem + 5120 + lane;
#pragma unroll
    for (int kt = 0; kt < 8; ++kt) {
      f16x8 a = A4[kt * 64];
      a4L = __builtin_amdgcn_mfma_f32_32x32x16_f16(a, B4L[kt], a4L, 0, 0, 0);
      a4H = __builtin_amdgcn_mfma_f32_32x32x16_f16(a, B4H[kt], a4H, 0, 0, 0);
    }
  }

  // ---- update: x_new = x + dy * mask (exact f32 x re-read, L2-hot) ----
  {
    const int row = r0 + wv;
    const float* xrb = x + (size_t)b * CHW + (row << 8);
    float* xob = xn + (size_t)b * CHW + (row << 8);
    const float* mrow = mask + (size_t)b * HW + (row << 8);
    {
      int col = c0 + pc;
      float mv = mrow[col];
#pragma unroll
      for (int r = 0; r < 8; ++r) {
        int ch = (r & 3) + 8 * (r >> 2) + 4 * hi;
        xob[((size_t)ch << 16) + col] = xrb[((size_t)ch << 16) + col] + a4L[r] * mv;
      }
    }
    {
      int col = c0 + 32 + pc;
      float mv = mrow[col];
#pragma unroll
      for (int r = 0; r < 8; ++r) {
        int ch = (r & 3) + 8 * (r >> 2) + 4 * hi;
        xob[((size_t)ch << 16) + col] = xrb[((size_t)ch << 16) + col] + a4H[r] * mv;
      }
    }
  }
}

// alive factor: row-block with LDS horizontal-max sharing; zero dead pixels
__global__ void alive_scale_k(const float* __restrict__ x, float* __restrict__ xn) {
  __shared__ float pm[4][258];
  const int col = threadIdx.x;
  const int row = blockIdx.x;
  const int b = blockIdx.y;
  const float NEG = -3.0e38f;
  float v0 = NEG, v1 = NEG, v2 = NEG, v3 = NEG;
  const size_t base0 = (size_t)b * CHW + ((size_t)row << 8) + col;
#pragma unroll
  for (int dr = -1; dr <= 1; ++dr) {
    int rr = row + dr;
    if ((unsigned)rr < NH) {
      long o = (long)base0 + dr * NW;
      v0 = fmaxf(v0, x[o]);
      v1 = fmaxf(v1, x[o + HW]);
      v2 = fmaxf(v2, xn[o]);
      v3 = fmaxf(v3, xn[o + HW]);
    }
  }
  pm[0][col + 1] = v0;
  pm[1][col + 1] = v1;
  pm[2][col + 1] = v2;
  pm[3][col + 1] = v3;
  if (col == 0) {
#pragma unroll
    for (int f = 0; f < 4; ++f) { pm[f][0] = NEG; pm[f][257] = NEG; }
  }
  __syncthreads();
  float p0 = fmaxf(fmaxf(pm[0][col], pm[0][col + 1]), pm[0][col + 2]);
  float p1 = fmaxf(fmaxf(pm[1][col], pm[1][col + 1]), pm[1][col + 2]);
  float p2 = fmaxf(fmaxf(pm[2][col], pm[2][col + 1]), pm[2][col + 2]);
  float p3 = fmaxf(fmaxf(pm[3][col], pm[3][col + 1]), pm[3][col + 2]);
  bool alive = ((fabsf(p0) + fabsf(p1)) > 0.01f) && ((fabsf(p2) + fabsf(p3)) > 0.01f);
  if (!alive) {
#pragma unroll
    for (int ch = 0; ch < NCH; ++ch) xn[base0 + ((size_t)ch << 16)] = 0.f;
  }
}

extern "C" void kernel_launch(void* const* d_in, const int* in_sizes, int n_in,
                              void* d_out, int out_size, void* d_ws, size_t ws_size,
                              hipStream_t stream) {
  const float* x    = (const float*)d_in[0];
  const float* w1   = (const float*)d_in[1];
  const float* b1   = (const float*)d_in[2];
  const float* w2   = (const float*)d_in[3];
  const float* b2   = (const float*)d_in[4];
  const float* w3   = (const float*)d_in[5];
  const float* b3   = (const float*)d_in[6];
  const float* w4   = (const float*)d_in[7];
  const float* mask = (const float*)d_in[8];

  float* wsf = (float*)d_ws;
  float* xn = (float*)d_out;

  hipFuncSetAttribute(reinterpret_cast<const void*>(nca_mlp_k),
                      hipFuncAttributeMaxDynamicSharedMemorySize, LDS_TOTAL);

  prep_k<<<178, 256, 0, stream>>>(w1, w2, w3, w4, b1, b2, b3, wsf);
  nca_mlp_k<<<dim3(NW / 64, NH / 8, NB), 512, LDS_TOTAL, stream>>>(x, wsf, mask, xn);
  alive_scale_k<<<dim3(NH, NB), 256, 0, stream>>>(x, xn);
}

// Round 9
// 419.028 us; speedup vs baseline: 6.7869x; 1.0096x over previous
//
#include <hip/hip_runtime.h>

typedef _Float16 f16;
typedef f16 f16x2 __attribute__((ext_vector_type(2)));
typedef f16 f16x8 __attribute__((ext_vector_type(8)));
typedef float f32x4 __attribute__((ext_vector_type(4)));
typedef float f32x16 __attribute__((ext_vector_type(16)));
typedef unsigned int uint;

#define NCH 16
#define NB 32
#define NH 256
#define NW 256
#define HW 65536
#define CHW 1048576

// weight image (f16 A-frags + f32 bias frags): f16x8 idx WF1=0, WF2=1024, WF3=3072, WF4=5120
#define BIAS_BYTE 90112
#define WS_BYTES 91648
// x tile: f32 [ch16][rr10][cc66], staged by global_load_lds DMA
#define XT_OFF 91648
#define XT_FLOATS (16*10*66)
#define LDS_TOTAL (WS_BYTES + XT_FLOATS*4)   // 133888

__global__ void prep_k(const float* __restrict__ w1, const float* __restrict__ w2,
                       const float* __restrict__ w3, const float* __restrict__ w4,
                       const float* __restrict__ b1, const float* __restrict__ b2,
                       const float* __restrict__ b3, float* __restrict__ wsf) {
  f16* wf = (f16*)wsf;
  int id = blockIdx.x * 256 + threadIdx.x;
  if (id < 8192) {
    int j = id & 7, l = (id >> 3) & 63, mt = (id >> 9) & 3, kt = id >> 11;
    int o = mt * 32 + (l & 31), c = kt * 16 + (l >> 5) * 8 + j;
    wf[id] = (f16)w1[o * 64 + c];
  } else if (id < 24576) {
    int t = id - 8192;
    int j = t & 7, l = (t >> 3) & 63, mt = (t >> 9) & 3, kt = t >> 11;
    int o = mt * 32 + (l & 31), c = kt * 16 + (l >> 5) * 8 + j;
    wf[8192 + t] = (f16)w2[o * 128 + c];
  } else if (id < 40960) {
    int t = id - 24576;
    int j = t & 7, l = (t >> 3) & 63, mt = (t >> 9) & 3, kt = t >> 11;
    int o = mt * 32 + (l & 31), c = kt * 16 + (l >> 5) * 8 + j;
    wf[24576 + t] = (f16)w3[o * 128 + c];
  } else if (id < 45056) {
    int t = id - 40960;
    int j = t & 7, l = (t >> 3) & 63, kt = t >> 9;
    int m = l & 31, hh = l >> 5;
    int c = kt * 16 + hh * 8 + j;
    wf[40960 + t] = (m < 16) ? (f16)w4[m * 128 + c] : (f16)0.f;
  } else if (id < 45440) {
    int t = id - 45056;
    int r = t & 15, hh = (t >> 4) & 1, mt = (t >> 5) & 3, ly = t >> 7;
    const float* bb = (ly == 0) ? b1 : (ly == 1) ? b2 : b3;
    ((float*)((unsigned char*)wsf + BIAS_BYTE))[t] =
        bb[mt * 32 + (r & 3) + 8 * (r >> 2) + 4 * hh];
  }
}

__device__ __forceinline__ void pl32swap(uint& a, uint& b) {
  asm volatile("v_permlane32_swap_b32 %0, %1" : "+v"(a), "+v"(b));
}

__device__ __forceinline__ f16x8 mk8(uint a, uint b, uint c, uint d) {
  union { uint u[4]; f16x8 v; } z;
  z.u[0] = a; z.u[1] = b; z.u[2] = c; z.u[3] = d;
  return z.v;
}

__device__ __forceinline__ void gload_lds4(const float* g, float* l) {
  __builtin_amdgcn_global_load_lds(
      (const __attribute__((address_space(1))) unsigned int*)(const void*)g,
      (__attribute__((address_space(3))) unsigned int*)(void*)l, 4, 0, 0);
}

// Dual-half layer: each A-frag ds_read feeds 2 MFMAs (halves L and H)
template <int NKT>
__device__ __forceinline__ void gemm2(const unsigned char* __restrict__ smem,
                                      int wfFragBase, int biasFloatOff, int lane, int hi,
                                      const f16x8* __restrict__ BL,
                                      const f16x8* __restrict__ BH,
                                      f32x16 accL[4], f32x16 accH[4]) {
  const float* bf = (const float*)(smem + BIAS_BYTE) + biasFloatOff;
#pragma unroll
  for (int mt = 0; mt < 4; ++mt) {
#pragma unroll
    for (int q = 0; q < 4; ++q) {
      f32x4 bv = *(const f32x4*)(bf + (mt * 2 + hi) * 16 + q * 4);
#pragma unroll
      for (int e = 0; e < 4; ++e) { accL[mt][q * 4 + e] = bv[e]; accH[mt][q * 4 + e] = bv[e]; }
    }
  }
  const f16x8* A = (const f16x8*)smem + wfFragBase + lane;
#pragma unroll
  for (int kt = 0; kt < NKT; ++kt) {
#pragma unroll
    for (int mt = 0; mt < 4; ++mt) {
      f16x8 a = A[(kt * 4 + mt) * 64];
      accL[mt] = __builtin_amdgcn_mfma_f32_32x32x16_f16(a, BL[kt], accL[mt], 0, 0, 0);
      accH[mt] = __builtin_amdgcn_mfma_f32_32x32x16_f16(a, BH[kt], accH[mt], 0, 0, 0);
    }
  }
}

__device__ __forceinline__ void epilogue_swap(const f32x16 acc[4], f16x8 Bn[8]) {
  uint w[32];
#pragma unroll
  for (int mt = 0; mt < 4; ++mt) {
#pragma unroll
    for (int i = 0; i < 8; ++i) {
      float v0 = acc[mt][2 * i], v1 = acc[mt][2 * i + 1];
      v0 = fmaxf(v0, 0.01f * v0);
      v1 = fmaxf(v1, 0.01f * v1);
      f16x2 t; t[0] = (f16)v0; t[1] = (f16)v1;
      w[mt * 8 + i] = __builtin_bit_cast(uint, t);
    }
  }
#pragma unroll
  for (int kt = 0; kt < 8; ++kt) {
    int mt = kt >> 1, sub = kt & 1;
    int W = mt * 8 + sub * 4;
    uint a0 = w[W], a1 = w[W + 1], a2 = w[W + 2], a3 = w[W + 3];
    pl32swap(a0, a2);
    pl32swap(a1, a3);
    Bn[kt] = mk8(a0, a1, a2, a3);
  }
}

// perception for one 32-px half from f32 tile: stencil math -> L1 B-frags
__device__ __forceinline__ void perception_f32(const float* __restrict__ xt,
                                               int wv, int pc, int hi, int h, f16x8 B1h[4]) {
  const int px = h * 32 + pc;
  uint yw[16];
#pragma unroll
  for (int kt = 0; kt < 4; ++kt) {
#pragma unroll
    for (int cp = 0; cp < 2; ++cp) {
      int c = kt * 4 + hi * 2 + cp;
      const float* xr = &xt[(c * 10 + wv) * 66 + px];
      float v00 = xr[0],   v01 = xr[1],   v02 = xr[2];
      float v10 = xr[66],  v11 = xr[67],  v12 = xr[68];
      float v20 = xr[132], v21 = xr[133], v22 = xr[134];
      float rs0 = v00 + v01 + v02, rs2 = v20 + v21 + v22;
      float fsx = (v02 - v00) + (v22 - v20) + 2.f * (v12 - v10);
      float fsy = (rs2 - rs0) + (v21 - v01);
      float flap = (rs0 + rs2 + v10 + v12) - 8.f * v11;
      f16x2 t0; t0[0] = (f16)v11; t0[1] = (f16)fsx;
      f16x2 t1; t1[0] = (f16)fsy; t1[1] = (f16)flap;
      yw[kt * 4 + cp * 2 + 0] = __builtin_bit_cast(uint, t0);
      yw[kt * 4 + cp * 2 + 1] = __builtin_bit_cast(uint, t1);
    }
  }
#pragma unroll
  for (int kt = 0; kt < 4; ++kt)
    B1h[kt] = mk8(yw[kt * 4], yw[kt * 4 + 1], yw[kt * 4 + 2], yw[kt * 4 + 3]);
}

// issue DMA for one tile's interior (rows split across 8 waves); zero OOB rows
__device__ __forceinline__ void issue_tile_dma(const float* __restrict__ xb,
                                               float* __restrict__ xt,
                                               int cx, int ry, int wv, int lane) {
  const int gc0 = cx * 64;
#pragma unroll
  for (int i = 0; i < 20; ++i) {
    int row = wv * 20 + i;           // 0..159 = ch*10 + rr
    int ch = row / 10;
    int rr = row - ch * 10;
    int gr = ry * 8 + rr - 1;
    float* ldst = xt + row * 66 + 1;
    if ((unsigned)gr < (unsigned)NH) {
      const float* g = xb + ((size_t)ch << 16) + (gr << 8) + gc0 + lane;
      gload_lds4(g, ldst);
    } else {
      ldst[lane] = 0.f;
    }
  }
}

// edge-column fixup: load early (reg), store late
__device__ __forceinline__ float fixup_load(const float* __restrict__ xb,
                                            int cx, int ry, int tid) {
  if (tid >= 320) return 0.f;
  int row = tid >> 1, side = tid & 1;
  int ch = row / 10;
  int rr = row - ch * 10;
  int gr = ry * 8 + rr - 1;
  int gc = cx * 64 - 1 + side * 65;
  float v = 0.f;
  if ((unsigned)gr < (unsigned)NH && (unsigned)gc < (unsigned)NW)
    v = xb[((size_t)ch << 16) + (gr << 8) + gc];
  return v;
}

__device__ __forceinline__ void fixup_store(float* __restrict__ xt, int tid, float v) {
  if (tid < 320) {
    int row = tid >> 1, side = tid & 1;
    xt[row * 66 + side * 65] = v;
  }
}

__global__ __launch_bounds__(512, 2)
void nca_mlp_k(const float* __restrict__ x, const float* __restrict__ wsf,
               const float* __restrict__ mask, float* __restrict__ xn) {
  extern __shared__ unsigned char smem[];
  float* xt = (float*)(smem + XT_OFF);
  const int tid = threadIdx.x;
  const int lane = tid & 63;
  const int wv = tid >> 6;     // 0..7 = tile row
  const int pc = lane & 31;
  const int hi = lane >> 5;

  const int tile0 = blockIdx.x * 16;
  const int b = tile0 >> 7;                 // constant per block
  const float* xb = x + (size_t)b * CHW;
  float* xnb = xn + (size_t)b * CHW;
  const float* mb = mask + (size_t)b * HW;

  // ---- stage weights+bias once (linear b128 copy) ----
  {
    const uint4* src = (const uint4*)wsf;
    uint4* dst = (uint4*)smem;
    for (int i = tid; i < WS_BYTES / 16; i += 512) dst[i] = src[i];
  }
  // ---- prefetch first tile ----
  {
    int cx = tile0 & 3, ry = (tile0 >> 2) & 31;
    issue_tile_dma(xb, xt, cx, ry, wv, lane);
    float fv = fixup_load(xb, cx, ry, tid);
    fixup_store(xt, tid, fv);   // auto-waits its own load
  }
  __syncthreads();              // drains vmcnt (DMA) + lgkm (weights, fixup)

  for (int t = 0; t < 16; ++t) {
    const int tile = tile0 + t;
    const int cx = tile & 3, ry = (tile >> 2) & 31;

    // ---- perception (sole consumer of xt) ----
    f16x8 B1L[4], B1H[4];
    perception_f32(xt, wv, pc, hi, 0, B1L);
    perception_f32(xt, wv, pc, hi, 1, B1H);
    __syncthreads();            // everyone done reading xt

    // ---- issue next tile's DMA; it drains at the iteration-end barrier ----
    float fv = 0.f;
    if (t < 15) {
      int cx2 = (tile + 1) & 3, ry2 = ((tile + 1) >> 2) & 31;
      issue_tile_dma(xb, xt, cx2, ry2, wv, lane);
      fv = fixup_load(xb, cx2, ry2, tid);
    }

    // ---- MLP chain ----
    f32x16 accL[4], accH[4];
    f16x8 B2L[8], B2H[8], B3L[8], B3H[8], B4L[8], B4H[8];

    gemm2<4>(smem, 0, 0, lane, hi, B1L, B1H, accL, accH);
    epilogue_swap(accL, B2L);
    epilogue_swap(accH, B2H);
    gemm2<8>(smem, 1024, 128, lane, hi, B2L, B2H, accL, accH);
    epilogue_swap(accL, B3L);
    epilogue_swap(accH, B3H);
    gemm2<8>(smem, 3072, 256, lane, hi, B3L, B3H, accL, accH);
    epilogue_swap(accL, B4L);
    epilogue_swap(accH, B4H);

    f32x16 a4L, a4H;
#pragma unroll
    for (int r = 0; r < 16; ++r) { a4L[r] = 0.f; a4H[r] = 0.f; }
    {
      const f16x8* A4 = (const f16x8*)smem + 5120 + lane;
#pragma unroll
      for (int kt = 0; kt < 8; ++kt) {
        f16x8 a = A4[kt * 64];
        a4L = __builtin_amdgcn_mfma_f32_32x32x16_f16(a, B4L[kt], a4L, 0, 0, 0);
        a4H = __builtin_amdgcn_mfma_f32_32x32x16_f16(a, B4H[kt], a4H, 0, 0, 0);
      }
    }

    // ---- update: x_new = x + dy * mask (exact f32 x re-read, L2-hot) ----
    {
      const int row = ry * 8 + wv;
      const float* xrb = xb + (row << 8);
      float* xob = xnb + (row << 8);
      const float* mrow = mb + (row << 8);
#pragma unroll
      for (int h = 0; h < 2; ++h) {
        int col = cx * 64 + h * 32 + pc;
        float mv = mrow[col];
#pragma unroll
        for (int r = 0; r < 8; ++r) {
          int ch = (r & 3) + 8 * (r >> 2) + 4 * hi;
          float dyv = h ? a4H[r] : a4L[r];
          xob[((size_t)ch << 16) + col] = xrb[((size_t)ch << 16) + col] + dyv * mv;
        }
      }
    }

    if (t < 15) fixup_store(xt, tid, fv);  // waits fv's load (long since landed)
    __syncthreads();            // drains DMA vmcnt + lgkm -> xt(t+1) ready
  }
}

// alive factor: row-block with LDS horizontal-max sharing; zero dead pixels
__global__ void alive_scale_k(const float* __restrict__ x, float* __restrict__ xn) {
  __shared__ float pm[4][258];
  const int col = threadIdx.x;
  const int row = blockIdx.x;
  const int b = blockIdx.y;
  const float NEG = -3.0e38f;
  float v0 = NEG, v1 = NEG, v2 = NEG, v3 = NEG;
  const size_t base0 = (size_t)b * CHW + ((size_t)row << 8) + col;
#pragma unroll
  for (int dr = -1; dr <= 1; ++dr) {
    int rr = row + dr;
    if ((unsigned)rr < NH) {
      long o = (long)base0 + dr * NW;
      v0 = fmaxf(v0, x[o]);
      v1 = fmaxf(v1, x[o + HW]);
      v2 = fmaxf(v2, xn[o]);
      v3 = fmaxf(v3, xn[o + HW]);
    }
  }
  pm[0][col + 1] = v0;
  pm[1][col + 1] = v1;
  pm[2][col + 1] = v2;
  pm[3][col + 1] = v3;
  if (col == 0) {
#pragma unroll
    for (int f = 0; f < 4; ++f) { pm[f][0] = NEG; pm[f][257] = NEG; }
  }
  __syncthreads();
  float p0 = fmaxf(fmaxf(pm[0][col], pm[0][col + 1]), pm[0][col + 2]);
  float p1 = fmaxf(fmaxf(pm[1][col], pm[1][col + 1]), pm[1][col + 2]);
  float p2 = fmaxf(fmaxf(pm[2][col], pm[2][col + 1]), pm[2][col + 2]);
  float p3 = fmaxf(fmaxf(pm[3][col], pm[3][col + 1]), pm[3][col + 2]);
  bool alive = ((fabsf(p0) + fabsf(p1)) > 0.01f) && ((fabsf(p2) + fabsf(p3)) > 0.01f);
  if (!alive) {
#pragma unroll
    for (int ch = 0; ch < NCH; ++ch) xn[base0 + ((size_t)ch << 16)] = 0.f;
  }
}

extern "C" void kernel_launch(void* const* d_in, const int* in_sizes, int n_in,
                              void* d_out, int out_size, void* d_ws, size_t ws_size,
                              hipStream_t stream) {
  const float* x    = (const float*)d_in[0];
  const float* w1   = (const float*)d_in[1];
  const float* b1   = (const float*)d_in[2];
  const float* w2   = (const float*)d_in[3];
  const float* b2   = (const float*)d_in[4];
  const float* w3   = (const float*)d_in[5];
  const float* b3   = (const float*)d_in[6];
  const float* w4   = (const float*)d_in[7];
  const float* mask = (const float*)d_in[8];

  float* wsf = (float*)d_ws;
  float* xn = (float*)d_out;

  hipFuncSetAttribute(reinterpret_cast<const void*>(nca_mlp_k),
                      hipFuncAttributeMaxDynamicSharedMemorySize, LDS_TOTAL);

  prep_k<<<178, 256, 0, stream>>>(w1, w2, w3, w4, b1, b2, b3, wsf);
  nca_mlp_k<<<256, 512, LDS_TOTAL, stream>>>(x, wsf, mask, xn);
  alive_scale_k<<<dim3(NH, NB), 256, 0, stream>>>(x, xn);
}